// Round 1
// baseline (52.656 us; speedup 1.0000x reference)
//
#include <hip/hip_runtime.h>
#include <hip/hip_bf16.h>

// PWL monotone interpolation, N=2097152, C=16, B=32.
// out[n,c] = ys[c,seg] + slope*(x[n,c]-xs[c,seg]) with seg from searchsorted(xs[c], x) clipped.
// Rewritten as out = a[c,seg]*x + b[c,seg] with precomputed a,b per segment.

#define C_CH 16
#define B_KN 32

// ---------------- setup: sort knots, cumsum ys, precompute per-segment a,b ----------------
// ws layout (floats): [0..511] xs (c*32+k), [512..1023] a (c*32+s), [1024..1535] b
__global__ __launch_bounds__(512) void pwl_setup_kernel(
    const float* __restrict__ xp, const float* __restrict__ y0,
    const float* __restrict__ dy, float* __restrict__ ws) {
    __shared__ float s_x[C_CH][B_KN];
    __shared__ float s_xs[C_CH][B_KN];
    __shared__ float s_ys[C_CH][B_KN];
    int t = threadIdx.x;
    int c = t >> 5;   // 0..15
    int k = t & 31;   // 0..31
    float v = xp[c * B_KN + k];
    s_x[c][k] = v;
    __syncthreads();
    // rank-sort: stable rank of v within channel c
    int rank = 0;
#pragma unroll
    for (int j = 0; j < B_KN; ++j) {
        float u = s_x[c][j];
        rank += (u < v || (u == v && j < k)) ? 1 : 0;
    }
    s_xs[c][rank] = v;
    // ys[k] = y0 + sum_{j<k} |dy[j]|   (serial per thread; tiny, L1/L2-cached)
    float acc = y0[c];
    for (int j = 0; j < k; ++j) acc += fabsf(dy[c * (B_KN - 1) + j]);
    s_ys[c][k] = acc;
    __syncthreads();
    ws[c * B_KN + k] = s_xs[c][k];
    if (k < B_KN - 1) {
        float x0 = s_xs[c][k], x1 = s_xs[c][k + 1];
        float ya = s_ys[c][k], yb = s_ys[c][k + 1];
        float a = (yb - ya) / (x1 - x0);
        float b = ya - a * x0;
        ws[512 + c * B_KN + k]  = a;
        ws[1024 + c * B_KN + k] = b;
    }
}

// ---------------- main: grid-stride float4, LDS-cached params, branchless search ----------------
__global__ __launch_bounds__(256) void pwl_main_kernel(
    const float4* __restrict__ x, float4* __restrict__ out,
    const float* __restrict__ ws, int n4) {
    __shared__ float s_xs[C_CH][B_KN + 1];  // pad to 33 to spread banks
    __shared__ float s_a[C_CH][B_KN];
    __shared__ float s_b[C_CH][B_KN];
    for (int i = threadIdx.x; i < C_CH * B_KN; i += 256) {
        int c = i >> 5, k = i & 31;
        s_xs[c][k] = ws[i];
        s_a[c][k]  = ws[512 + i];
        s_b[c][k]  = ws[1024 + i];
    }
    __syncthreads();

    int tid = blockIdx.x * 256 + threadIdx.x;
    int stride = gridDim.x * 256;
    for (int i = tid; i < n4; i += stride) {
        float4 v = x[i];
        // float4 i covers flat elements 4i..4i+3; channel = flat & 15
        int c0 = (i & 3) << 2;
        float xv[4] = {v.x, v.y, v.z, v.w};
        float r[4];
#pragma unroll
        for (int j = 0; j < 4; ++j) {
            int c = c0 + j;
            float xq = xv[j];
            const float* xs = s_xs[c];
            // branchless lower_bound: pos = min(#{xs[i] < xq}, 31)
            int pos = 0;
#pragma unroll
            for (int s = 16; s >= 1; s >>= 1)
                pos += (xs[pos + s - 1] < xq) ? s : 0;
            int seg = (pos > 1 ? pos : 1) - 1;  // clip(searchsorted,1,31)-1
            r[j] = fmaf(s_a[c][seg], xq, s_b[c][seg]);
        }
        out[i] = make_float4(r[0], r[1], r[2], r[3]);
    }
}

extern "C" void kernel_launch(void* const* d_in, const int* in_sizes, int n_in,
                              void* d_out, int out_size, void* d_ws, size_t ws_size,
                              hipStream_t stream) {
    const float* x  = (const float*)d_in[0];
    const float* xp = (const float*)d_in[1];
    const float* y0 = (const float*)d_in[2];
    const float* dy = (const float*)d_in[3];
    float* out = (float*)d_out;
    float* ws  = (float*)d_ws;

    pwl_setup_kernel<<<1, 512, 0, stream>>>(xp, y0, dy, ws);

    int n4 = in_sizes[0] / 4;  // 8388608
    int blocks = (n4 + 255) / 256;
    if (blocks > 2048) blocks = 2048;  // grid-stride, ~8 blocks/CU
    pwl_main_kernel<<<blocks, 256, 0, stream>>>((const float4*)x, (float4*)out, ws, n4);
}